// Round 8
// baseline (249.563 us; speedup 1.0000x reference)
//
#include <hip/hip_runtime.h>

typedef __bf16 bf16x8 __attribute__((ext_vector_type(8)));
typedef float f32x4 __attribute__((ext_vector_type(4)));
typedef unsigned short u16x8 __attribute__((ext_vector_type(8)));

#define S_LEN 2048
#define NHEAD 16
#define HDIM  64
#define EMB   1024

__device__ __forceinline__ ushort f2b(float v) {
  union { float f; unsigned u; } x; x.f = v;
  unsigned r = (x.u + 0x7fffu + ((x.u >> 16) & 1u)) >> 16;
  return (ushort)r;
}

// pack two floats as truncated bf16 pair (a -> low16, b -> high16)
__device__ __forceinline__ unsigned packtrunc(float a, float b) {
  union { float f; unsigned u; } x, y; x.f = a; y.f = b;
  return (x.u >> 16) | (y.u & 0xFFFF0000u);
}

// async global->LDS, 16B per lane; LDS dest = wave-uniform base + lane*16
typedef const __attribute__((address_space(1))) unsigned int* gp1_t;
typedef __attribute__((address_space(3))) unsigned int* lp3_t;
__device__ __forceinline__ void gld16(const ushort* g, const ushort* l) {
  __builtin_amdgcn_global_load_lds((gp1_t)(unsigned long long)(uintptr_t)g,
                                   (lp3_t)(unsigned int)(uintptr_t)l, 16, 0, 0);
}

// ---------- fused prep: cast x -> bf16 (z==4) + transpose/cast weights (z<4) ----------
__global__ __launch_bounds__(256) void prep_kernel(
    const float* __restrict__ x, const float* __restrict__ W0,
    const float* __restrict__ W1, const float* __restrict__ W2,
    const float* __restrict__ W3, ushort* __restrict__ xb,
    ushort* __restrict__ Wt0, ushort* __restrict__ Wt1,
    ushort* __restrict__ Wt2, ushort* __restrict__ Wt3, float scale0) {
  const int z = blockIdx.z;
  if (z == 4) {  // x cast: 1024 blocks x 8192 floats
    size_t base = ((size_t)(blockIdx.y * 32 + blockIdx.x)) * 8192 + threadIdx.x * 4;
#pragma unroll
    for (int i = 0; i < 8; ++i) {
      float4 v = *(const float4*)(x + base + i * 1024);
      ushort4 o;
      o.x = f2b(v.x); o.y = f2b(v.y); o.z = f2b(v.z); o.w = f2b(v.w);
      *(ushort4*)(xb + base + i * 1024) = o;
    }
    return;
  }
  __shared__ float t[32][33];
  const float* W = z == 0 ? W0 : (z == 1 ? W1 : (z == 2 ? W2 : W3));
  ushort* Wt = z == 0 ? Wt0 : (z == 1 ? Wt1 : (z == 2 ? Wt2 : Wt3));
  const float scale = z == 0 ? scale0 : 1.0f;
  int k0 = blockIdx.x * 32, n0 = blockIdx.y * 32;
  int c = threadIdx.x & 31, r0 = threadIdx.x >> 5;
#pragma unroll
  for (int i = 0; i < 4; ++i) {
    int r = r0 + i * 8;
    t[r][c] = W[(size_t)(k0 + r) * EMB + n0 + c];
  }
  __syncthreads();
#pragma unroll
  for (int i = 0; i < 4; ++i) {
    int r = r0 + i * 8;
    Wt[(size_t)(n0 + r) * EMB + k0 + c] = f2b(t[c][r] * scale);
  }
}

// ---------------- GEMM: C[M,N] = A[M,K] * Bt[N,K]^T, bf16 MFMA ----------------
// m97 structure: global_load_lds dwordx4 staging, unpadded BK=32 LDS,
// double-buffered, one barrier per K-iter.
// EPI==0: blockIdx.y selects Q (0-7) / K (8-15) / V (16-23); Q,K written
//         [b,h,s,d] bf16; V written TRANSPOSED [b,h,d,s] (packed uint2 stores).
// EPI==1: fp32 out + bias.
template <int EPI>
__global__ __launch_bounds__(256) void gemm_kernel(
    const ushort* __restrict__ A, const ushort* __restrict__ Bt, int K, int N,
    ushort* __restrict__ outQ, ushort* __restrict__ outK, ushort* __restrict__ outVt,
    float* __restrict__ outF, const float* __restrict__ bias) {
  __shared__ ushort As[2][128 * 32];
  __shared__ ushort Bs[2][128 * 32];
  const int tid = threadIdx.x;
  const int lane = tid & 63, ln = lane & 15, quad = lane >> 4;
  const int wave = tid >> 6, wm = wave >> 1, wn = wave & 1;
  const long m0 = (long)blockIdx.x * 128, n0 = (long)blockIdx.y * 128;

  const int sr = lane >> 2, sc = (lane & 3) * 8;
  const ushort* AgL = A + (m0 + 32 * wave + sr) * (long)K + sc;
  const ushort* BgL = Bt + (n0 + 32 * wave + sr) * (long)K + sc;

  f32x4 acc[4][4] = {};
  const int KT = K >> 5;

  {
    ushort* as = &As[0][32 * wave * 32];
    ushort* bs = &Bs[0][32 * wave * 32];
    gld16(AgL, as);
    gld16(AgL + 16 * (long)K, as + 16 * 32);
    gld16(BgL, bs);
    gld16(BgL + 16 * (long)K, bs + 16 * 32);
  }
  __syncthreads();

  for (int kt = 0; kt < KT; ++kt) {
    if (kt + 1 < KT) {
      const int nb = (kt + 1) & 1;
      const ushort* a = AgL + (kt + 1) * 32;
      const ushort* b = BgL + (kt + 1) * 32;
      ushort* as = &As[nb][32 * wave * 32];
      ushort* bs = &Bs[nb][32 * wave * 32];
      gld16(a, as);
      gld16(a + 16 * (long)K, as + 16 * 32);
      gld16(b, bs);
      gld16(b + 16 * (long)K, bs + 16 * 32);
    }
    const ushort* Ac = &As[kt & 1][0];
    const ushort* Bc = &Bs[kt & 1][0];
    bf16x8 af[4], bf[4];
#pragma unroll
    for (int mt = 0; mt < 4; ++mt)
      af[mt] = *(const bf16x8*)(Ac + (wm * 64 + mt * 16 + ln) * 32 + quad * 8);
#pragma unroll
    for (int nt = 0; nt < 4; ++nt)
      bf[nt] = *(const bf16x8*)(Bc + (wn * 64 + nt * 16 + ln) * 32 + quad * 8);
#pragma unroll
    for (int mt = 0; mt < 4; ++mt)
#pragma unroll
      for (int nt = 0; nt < 4; ++nt)
        acc[mt][nt] = __builtin_amdgcn_mfma_f32_16x16x32_bf16(af[mt], bf[nt], acc[mt][nt], 0, 0, 0);
    __syncthreads();
  }

  if (EPI == 0) {
    const int sel = (int)(n0 >> 10);  // block-uniform: 1024 | 128*8
    if (sel == 2) {
      // V: write transposed [bh][d][s]; 4 regs = 4 consecutive s -> uint2
#pragma unroll
      for (int mt = 0; mt < 4; ++mt) {
        const long mbase = m0 + wm * 64 + mt * 16 + quad * 4;
        const long bb = mbase >> 11, s = mbase & 2047;
#pragma unroll
        for (int nt = 0; nt < 4; ++nt) {
          const int nn = (int)((n0 & 1023) + wn * 64 + nt * 16 + ln);
          const int h = nn >> 6, d = nn & 63;
          uint2 val;
          val.x = (unsigned)f2b(acc[mt][nt][0]) | ((unsigned)f2b(acc[mt][nt][1]) << 16);
          val.y = (unsigned)f2b(acc[mt][nt][2]) | ((unsigned)f2b(acc[mt][nt][3]) << 16);
          *(uint2*)(outVt + (((bb * NHEAD + h) * (long)HDIM + d) * S_LEN) + s) = val;
        }
      }
    } else {
      ushort* dst = sel == 0 ? outQ : outK;
#pragma unroll
      for (int mt = 0; mt < 4; ++mt) {
#pragma unroll
        for (int nt = 0; nt < 4; ++nt) {
          const int nn = (int)((n0 & 1023) + wn * 64 + nt * 16 + ln);
          const int h = nn >> 6, d = nn & 63;
#pragma unroll
          for (int r = 0; r < 4; ++r) {
            const long m = m0 + wm * 64 + mt * 16 + quad * 4 + r;
            const long bb = m >> 11, s = m & 2047;
            dst[(((bb * NHEAD + h) * S_LEN) + s) * HDIM + d] = f2b(acc[mt][nt][r]);
          }
        }
      }
    }
  } else {
#pragma unroll
    for (int mt = 0; mt < 4; ++mt) {
#pragma unroll
      for (int nt = 0; nt < 4; ++nt) {
#pragma unroll
        for (int r = 0; r < 4; ++r) {
          const long m = m0 + wm * 64 + mt * 16 + quad * 4 + r;
          const long n = n0 + wn * 64 + nt * 16 + ln;
          outF[m * (long)N + n] = acc[mt][nt][r] + bias[n];
        }
      }
    }
  }
}

// ---------------- flash attention, v8: 64 q-rows per wave ----------------
// Q,K: [bh][s][d] bf16 (Q pre-scaled by log2e/8 via Wq).  Vt: [bh][d][s] bf16.
// Y: [b][s][h][d] bf16.
// Block: 256 q-rows, 4 waves x 64 rows (four 16-row halves). K/V fragment
// reads hoisted to registers ONCE per tile and shared across all 4 halves
// (LDS reads/q-row -40% vs v7); staging traffic per q-row halves.
// S^T = K x Q^T per half -> lane holds 4 consecutive keys -> one b64 P-write.
// 64-key tiles, gld16 double-buffered -> one barrier per tile.
// l-sum via MFMA against ones.  LDS 68 KB -> 2 blocks/CU; grid 512 = all
// blocks resident; y->qb map pairs heavy+light blocks (sum 36 tiles/CU).
__global__ __launch_bounds__(256, 2) void attn_kernel(const ushort* __restrict__ Q,
                                                      const ushort* __restrict__ Kg,
                                                      const ushort* __restrict__ Vt,
                                                      ushort* __restrict__ Y) {
  __shared__ alignas(16) ushort Ks[2][2 * 64 * 32];  // [buf][d-half][key][32 d]
  __shared__ alignas(16) ushort Vs[2][2 * 64 * 32];  // [buf][key-half][d][32 keys]
  __shared__ alignas(16) ushort Ps[4 * 4 * 16 * 72]; // [wave][half][16 q][72 keys]
  const int tid = threadIdx.x;
  const int wave = tid >> 6, lane = tid & 63, ln = lane & 15, quad = lane >> 4;
  const int bh = blockIdx.x;
  const int yb = (int)blockIdx.y;
  const int qb = yb < 4 ? 7 - yb : yb - 4;  // pair (7,0),(6,1),(5,2),(4,3) per CU
  const int q0 = qb * 256;
  const size_t base = (size_t)bh * S_LEN * HDIM;
  const int ntiles = 4 * qb + 4;
  const int qbase = q0 + wave * 64;  // this wave's 64 q-rows

  const u16x8 ob = {0x3F80, 0x3F80, 0x3F80, 0x3F80, 0x3F80, 0x3F80, 0x3F80, 0x3F80};
  const bf16x8 ones = __builtin_bit_cast(bf16x8, ob);

  bf16x8 qf[4][2];
#pragma unroll
  for (int h = 0; h < 4; ++h)
#pragma unroll
    for (int ks2 = 0; ks2 < 2; ++ks2)
      qf[h][ks2] = *(const bf16x8*)(Q + base + (size_t)(qbase + h * 16 + ln) * HDIM +
                                    ks2 * 32 + quad * 8);

  f32x4 acc[4][4] = {};
  f32x4 accl[4] = {};

  const int sr = lane >> 2, sc = (lane & 3) * 8;
  const ushort* KgL = Kg + base + (size_t)(16 * wave + sr) * HDIM + sc;
  const ushort* VgL = Vt + base + (size_t)(16 * wave + sr) * S_LEN + sc;

  {
    ushort* kb = &Ks[0][16 * wave * 32];
    ushort* vb = &Vs[0][16 * wave * 32];
    gld16(KgL, kb);
    gld16(KgL + 32, kb + 2048);
    gld16(VgL, vb);
    gld16(VgL + 32, vb + 2048);
  }
  __syncthreads();

  ushort* Pw = Ps + wave * 4608;

  for (int kt = 0; kt < ntiles; ++kt) {
    const int cur = kt & 1;
    const int k0 = kt * 64;
    if (kt + 1 < ntiles) {
      const int nb = cur ^ 1;
      const size_t k1 = (size_t)(k0 + 64);
      ushort* kb = &Ks[nb][16 * wave * 32];
      ushort* vb = &Vs[nb][16 * wave * 32];
      gld16(KgL + k1 * HDIM, kb);
      gld16(KgL + k1 * HDIM + 32, kb + 2048);
      gld16(VgL + k1, vb);
      gld16(VgL + k1 + 32, vb + 2048);
    }
    const ushort* Kc = &Ks[cur][0];
    const ushort* Vc = &Vs[cur][0];

    if (k0 < qbase + 64) {  // wave-uniform: some q-row in wave has live keys
      // K-fragments once per tile, shared by all 4 q-halves
      bf16x8 ak[2][4];
#pragma unroll
      for (int ks2 = 0; ks2 < 2; ++ks2)
#pragma unroll
        for (int nt = 0; nt < 4; ++nt)
          ak[ks2][nt] = *(const bf16x8*)(Kc + ks2 * 2048 + (nt * 16 + ln) * 32 + quad * 8);

      asm volatile("" ::: "memory");
#pragma unroll
      for (int h = 0; h < 4; ++h) {
        if (k0 > qbase + h * 16 + 15) continue;  // half fully masked (wave-uniform)
        // S^T[key][q]: A = K-frag (m=key), B = Q-frag (n=q)
        f32x4 sT[4] = {};
#pragma unroll
        for (int ks2 = 0; ks2 < 2; ++ks2)
#pragma unroll
          for (int nt = 0; nt < 4; ++nt)
            sT[nt] = __builtin_amdgcn_mfma_f32_16x16x32_bf16(ak[ks2][nt], qf[h][ks2], sT[nt], 0, 0, 0);

        if (k0 + 63 > qbase + h * 16) {  // diagonal for this half: mask
          const int thr = qbase + h * 16 + ln - k0 - quad * 4;  // mask if nt*16+r > thr
#pragma unroll
          for (int nt = 0; nt < 4; ++nt)
#pragma unroll
            for (int r = 0; r < 4; ++r)
              if (nt * 16 + r > thr) sT[nt][r] = -3.0e38f;
        }

        // exp2 + pack 4 consecutive keys -> one b64 write into P[h][q][key]
#pragma unroll
        for (int nt = 0; nt < 4; ++nt) {
          uint2 w;
          w.x = packtrunc(__builtin_amdgcn_exp2f(sT[nt][0]), __builtin_amdgcn_exp2f(sT[nt][1]));
          w.y = packtrunc(__builtin_amdgcn_exp2f(sT[nt][2]), __builtin_amdgcn_exp2f(sT[nt][3]));
          *(uint2*)(Pw + h * 1152 + ln * 72 + nt * 16 + quad * 4) = w;
        }
      }
      asm volatile("" ::: "memory");

      // V-fragments once per tile, shared by all 4 q-halves
      bf16x8 bv[2][4];
#pragma unroll
      for (int ks2 = 0; ks2 < 2; ++ks2)
#pragma unroll
        for (int t2 = 0; t2 < 4; ++t2)
          bv[ks2][t2] = *(const bf16x8*)(Vc + ks2 * 2048 + (t2 * 16 + ln) * 32 + quad * 8);

#pragma unroll
      for (int h = 0; h < 4; ++h) {
        if (k0 > qbase + h * 16 + 15) continue;
#pragma unroll
        for (int ks2 = 0; ks2 < 2; ++ks2) {
          bf16x8 ap = *(const bf16x8*)(Pw + h * 1152 + ln * 72 + ks2 * 32 + quad * 8);
          accl[h] = __builtin_amdgcn_mfma_f32_16x16x32_bf16(ap, ones, accl[h], 0, 0, 0);
#pragma unroll
          for (int t2 = 0; t2 < 4; ++t2)
            acc[h][t2] = __builtin_amdgcn_mfma_f32_16x16x32_bf16(ap, bv[ks2][t2], acc[h][t2], 0, 0, 0);
        }
      }
    }
    __syncthreads();  // single barrier per tile (drains async stage too)
  }

  const long b = bh >> 4;
  const int hh = bh & 15;
#pragma unroll
  for (int h = 0; h < 4; ++h) {
#pragma unroll
    for (int r = 0; r < 4; ++r) {
      float inv = 1.0f / accl[h][r];
      const int qq = qbase + h * 16 + quad * 4 + r;
#pragma unroll
      for (int t2 = 0; t2 < 4; ++t2)
        Y[(((b * S_LEN + qq) * NHEAD) + hh) * HDIM + t2 * 16 + ln] = f2b(acc[h][t2][r] * inv);
    }
  }
}

extern "C" void kernel_launch(void* const* d_in, const int* in_sizes, int n_in,
                              void* d_out, int out_size, void* d_ws, size_t ws_size,
                              hipStream_t stream) {
  const float* x  = (const float*)d_in[0];
  const float* Wq = (const float*)d_in[1];
  const float* Wk = (const float*)d_in[2];
  const float* Wv = (const float*)d_in[3];
  const float* Wo = (const float*)d_in[4];
  const float* bo = (const float*)d_in[5];
  float* out = (float*)d_out;

  const size_t XE = (size_t)8192 * EMB;  // 8388608
  ushort* ws    = (ushort*)d_ws;
  ushort* xb    = ws;
  ushort* Wtqkv = xb + XE;
  ushort* Wto   = Wtqkv + 3 * 1048576;
  ushort* Qb    = Wto + 1048576;
  ushort* Kb    = Qb + XE;
  ushort* Vtb   = Kb + XE;
  ushort* Yb    = xb;  // alias: xb dead after QKV GEMM

  const float SCALE_Q = 1.4426950408889634f / 8.0f;  // log2(e)/sqrt(D)

  prep_kernel<<<dim3(32, 32, 5), 256, 0, stream>>>(
      x, Wq, Wk, Wv, Wo, xb, Wtqkv, Wtqkv + 1048576, Wtqkv + 2097152, Wto, SCALE_Q);

  gemm_kernel<0><<<dim3(64, 24), 256, 0, stream>>>(xb, Wtqkv, EMB, 3072,
                                                   Qb, Kb, Vtb, nullptr, nullptr);
  attn_kernel<<<dim3(64, 8), 256, 0, stream>>>(Qb, Kb, Vtb, Yb);
  gemm_kernel<1><<<dim3(64, 8), 256, 0, stream>>>(Yb, Wto, EMB, EMB,
                                                  nullptr, nullptr, nullptr, out, bo);
}